// Round 1
// baseline (1657.332 us; speedup 1.0000x reference)
//
#include <hip/hip_runtime.h>
#include <math.h>

// Problem constants (fixed by setup_inputs)
#define HEADS 8
#define DIM 64
#define E_PER_H 400000
#define NE (HEADS * E_PER_H)      // 3,200,000 edges total (flat)
#define NSEG 400000               // num_nodes * HEADS = 50000*8

// ws layout (floats):
//   [0,        NE)        e / z  (in place)
//   [NE,       NE+NSEG)   seg_max (float bits)
//   [NE+NSEG,  NE+2NSEG)  seg_sum

__device__ __forceinline__ void atomicMaxFloat(float* addr, float val) {
    // Standard signed/unsigned trick; works with -inf init.
    if (val >= 0.0f) {
        atomicMax((int*)addr, __float_as_int(val));
    } else {
        atomicMin((unsigned int*)addr, (unsigned int)__float_as_int(val));
    }
}

__global__ void init_segs(float* __restrict__ segmax, float* __restrict__ segsum) {
    int i = blockIdx.x * blockDim.x + threadIdx.x;
    if (i < NSEG) {
        ((int*)segmax)[i] = 0xFF800000;   // -inf
        segsum[i] = 0.0f;
    }
}

// 16 lanes per edge; lane i loads float4 #i of the 64-float row.
// A full wave (64 lanes) covers 4 consecutive edges -> 1024 contiguous bytes
// per vector-load instruction: perfectly coalesced.
__global__ void compute_e(const float* __restrict__ xi, const float* __restrict__ xj,
                          const float* __restrict__ a, const int* __restrict__ idx,
                          float* __restrict__ e_out, float* __restrict__ segmax) {
    long long t = (long long)blockIdx.x * blockDim.x + threadIdx.x;
    int g = (int)(t >> 4);       // edge id
    int sub = (int)(t & 15);     // float4 slot within the row
    if (g >= NE) return;
    int h = g / E_PER_H;

    const float4 vi = ((const float4*)xi)[(long long)g * 16 + sub];
    const float4 vj = ((const float4*)xj)[(long long)g * 16 + sub];
    // a is (H, 1, 2*DIM): a_l = a[h][0:64], a_r = a[h][64:128]. Tiny, L1-resident.
    const float4 al = ((const float4*)(a + h * 128))[sub];
    const float4 ar = ((const float4*)(a + h * 128 + 64))[sub];

    float s = vi.x * vj.x * al.x * ar.x
            + vi.y * vj.y * al.y * ar.y
            + vi.z * vj.z * al.z * ar.z
            + vi.w * vj.w * al.w * ar.w;

    // reduce across the 16 lanes of this edge (xor masks < 16 stay in-group)
    s += __shfl_xor(s, 1);
    s += __shfl_xor(s, 2);
    s += __shfl_xor(s, 4);
    s += __shfl_xor(s, 8);

    if (sub == 0) {
        e_out[g] = s;
        int seg = idx[g];
        atomicMaxFloat(&segmax[seg], s);
    }
}

__global__ void exp_and_sum(float* __restrict__ ez, const int* __restrict__ idx,
                            const float* __restrict__ segmax, float* __restrict__ segsum) {
    int g = blockIdx.x * blockDim.x + threadIdx.x;
    if (g >= NE) return;
    int seg = idx[g];
    float z = expf(ez[g] - segmax[seg]);
    ez[g] = z;
    atomicAdd(&segsum[seg], z);
}

__global__ void normalize(const float* __restrict__ z, const int* __restrict__ idx,
                          const float* __restrict__ segsum, float* __restrict__ out) {
    int g = blockIdx.x * blockDim.x + threadIdx.x;
    if (g >= NE) return;
    int seg = idx[g];
    out[g] = z[g] / (segsum[seg] + 1e-16f);
}

extern "C" void kernel_launch(void* const* d_in, const int* in_sizes, int n_in,
                              void* d_out, int out_size, void* d_ws, size_t ws_size,
                              hipStream_t stream) {
    const float* xi = (const float*)d_in[0];
    const float* xj = (const float*)d_in[1];
    const float* a  = (const float*)d_in[2];
    const int* edge_index = (const int*)d_in[3];   // (2, NE) int32 (harness converts)
    const int* idx = edge_index + NE;              // row 1 = target nodes

    float* ws = (float*)d_ws;
    float* ez     = ws;              // NE floats: e, then z in place
    float* segmax = ws + NE;         // NSEG floats
    float* segsum = ws + NE + NSEG;  // NSEG floats
    float* out = (float*)d_out;

    {
        int threads = 256;
        int blocks = (NSEG + threads - 1) / threads;
        init_segs<<<blocks, threads, 0, stream>>>(segmax, segsum);
    }
    {
        long long total = (long long)NE * 16;
        int threads = 256;
        int blocks = (int)((total + threads - 1) / threads);
        compute_e<<<blocks, threads, 0, stream>>>(xi, xj, a, idx, ez, segmax);
    }
    {
        int threads = 256;
        int blocks = (NE + threads - 1) / threads;
        exp_and_sum<<<blocks, threads, 0, stream>>>(ez, idx, segmax, segsum);
        normalize<<<blocks, threads, 0, stream>>>(ez, idx, segsum, out);
    }
}